// Round 24
// baseline (120.829 us; speedup 1.0000x reference)
//
#include <hip/hip_runtime.h>
#include <math.h>

#define Ddim 384
#define D4 96                      // Ddim/4
#define NUM_ITEMS 16384
#define NUM_CLUSTERS 256
#define MCS 128                    // MAX_CLUSTER_SIZE
#define NEG_INF_F (-1e9f)
#define NTOK 4096
#define TPB 8                      // tokens per compute block
#define NCB (NTOK / TPB)           // 512 compute blocks
#define NFILLB 2048                // fill blocks

__device__ __forceinline__ float dot4(const float4& a, const float4& b) {
    return a.x * b.x + a.y * b.y + a.z * b.z + a.w * b.w;
}
__device__ __forceinline__ void pin4(float4& v) {
    asm volatile("" : "+v"(v.x), "+v"(v.y), "+v"(v.z), "+v"(v.w));
}

// ---------- D1: pure fill (2048 blocks) + meta (block 2048) ----------
__global__ __launch_bounds__(256) void hs_fill_meta(
    const int* __restrict__ targets, const int* __restrict__ cluster_assign,
    float* __restrict__ dummy_out, int* __restrict__ wsI)
{
    const int tid = threadIdx.x;

    if (blockIdx.x == NFILLB) {
        __shared__ int cnt[NUM_CLUSTERS], scan[NUM_CLUSTERS], cur[NUM_CLUSTERS];
        cnt[tid] = 0; cur[tid] = 0;
        __syncthreads();
        int tcv[NTOK / 256];
        #pragma unroll
        for (int i = 0; i < NTOK / 256; ++i) {
            const int t = i * 256 + tid;
            const int tc = cluster_assign[targets[t]];
            tcv[i] = tc;
            atomicAdd(&cnt[tc], 1);
        }
        __syncthreads();
        scan[tid] = cnt[tid];
        __syncthreads();
        for (int d = 1; d < 256; d <<= 1) {
            const int v = (tid >= d) ? scan[tid - d] : 0;
            __syncthreads();
            scan[tid] += v;
            __syncthreads();
        }
        wsI[tid] = scan[tid] - cnt[tid];
        if (tid == 255) wsI[256] = NTOK;
        __syncthreads();
        #pragma unroll
        for (int i = 0; i < NTOK / 256; ++i) {
            const int t = i * 256 + tid;
            const int tc = tcv[i];
            const int p = atomicAdd(&cur[tc], 1);
            wsI[257 + (scan[tc] - cnt[tc]) + p] = t;
        }
        return;
    }

    const size_t base = (size_t)blockIdx.x * 256 + tid;
    float4 z; z.x = z.y = z.z = z.w = 0.f;
    float4* o4 = reinterpret_cast<float4*>(dummy_out) + base;
    #pragma unroll 8
    for (int i = 0; i < 32; ++i)
        o4[(size_t)i * (NFILLB * 256)] = z;
}

// ---------- D2: compute over cluster-sorted tokens, 8 tokens PER WAVE ----------
// 512 blocks x 256 thr (4 waves = 4 cluster-quarters). 32-lane D-split:
// hf[8][3] float4 = 96 VGPR -> one CE read serves 8 tokens (CE traffic
// 402 -> 201 MB, and no duplicate quarter reads within a block).
__global__ __launch_bounds__(256, 2) void hs_compute(
    const float* __restrict__ hidden,
    const float* __restrict__ item_emb,
    const float* __restrict__ cluster_emb,
    const float* __restrict__ item_mask,
    const int*   __restrict__ targets,
    const int*   __restrict__ cluster_assign,
    const int*   __restrict__ cluster_idx,
    const int*   __restrict__ in_cluster_id,
    const int*   __restrict__ wsI,
    float* __restrict__ ws)
{
    const int cb   = blockIdx.x;           // 0..511
    const int tid  = threadIdx.x;
    const int t0   = cb * TPB;
    const int lane = tid & 63;
    const int wave = tid >> 6;             // 0..3 = 64-cluster quarter
    const int q2   = lane >> 5;            // 2-cluster subgroup
    const int r5   = lane & 31;            // 32-lane D-split

    __shared__ float clog[TPB][NUM_CLUSTERS];   // 8 KB
    __shared__ float mlog[TPB][64];             // 2 KB

    const int* list = wsI + 257;            // cluster-sorted token ids

    // ---- per-lane h fragments: 8 tokens x 3 float4 (96 VGPR, pinned) ----
    const float4* h4 = reinterpret_cast<const float4*>(hidden);
    int tok[8];
    #pragma unroll
    for (int j = 0; j < 8; ++j) tok[j] = list[t0 + j];
    float4 hf[8][3];
    #pragma unroll
    for (int j = 0; j < 8; ++j)
        #pragma unroll
        for (int i = 0; i < 3; ++i) {
            hf[j][i] = h4[(size_t)tok[j] * D4 + i * 32 + r5];
            pin4(hf[j][i]);
        }

    // ---- cluster logits: 32 iters x 2 clusters x 8 tokens per wave ----
    const float4* ce4 = reinterpret_cast<const float4*>(cluster_emb);
    #pragma unroll 2
    for (int it = 0; it < 32; ++it) {
        const int c = wave * 64 + it * 2 + q2;
        float4 ce[3];
        #pragma unroll
        for (int i = 0; i < 3; ++i) ce[i] = ce4[(size_t)c * D4 + i * 32 + r5];
        float a0 = 0.f, a1 = 0.f, a2 = 0.f, a3 = 0.f;
        float a4 = 0.f, a5 = 0.f, a6 = 0.f, a7 = 0.f;
        #pragma unroll
        for (int i = 0; i < 3; ++i) {
            a0 += dot4(ce[i], hf[0][i]);
            a1 += dot4(ce[i], hf[1][i]);
            a2 += dot4(ce[i], hf[2][i]);
            a3 += dot4(ce[i], hf[3][i]);
            a4 += dot4(ce[i], hf[4][i]);
            a5 += dot4(ce[i], hf[5][i]);
            a6 += dot4(ce[i], hf[6][i]);
            a7 += dot4(ce[i], hf[7][i]);
        }
        // payload fold: 8 accs over 32 lanes, 5 shuffle steps.
        // step xor16: pack tokens {0..3}|{4..7} by bit4
        const bool h16 = (r5 & 16) != 0;
        float u0 = h16 ? a4 : a0, uS0 = h16 ? a0 : a4;
        float u1 = h16 ? a5 : a1, uS1 = h16 ? a1 : a5;
        float u2 = h16 ? a6 : a2, uS2 = h16 ? a2 : a6;
        float u3 = h16 ? a7 : a3, uS3 = h16 ? a3 : a7;
        u0 += __shfl_xor(uS0, 16);
        u1 += __shfl_xor(uS1, 16);
        u2 += __shfl_xor(uS2, 16);
        u3 += __shfl_xor(uS3, 16);
        // step xor8: pack {0,1}|{2,3} by bit3
        const bool h8 = (r5 & 8) != 0;
        float v0 = h8 ? u2 : u0, vS0 = h8 ? u0 : u2;
        float v1 = h8 ? u3 : u1, vS1 = h8 ? u1 : u3;
        v0 += __shfl_xor(vS0, 8);
        v1 += __shfl_xor(vS1, 8);
        // step xor4: pack {0}|{1} by bit2
        const bool h4b = (r5 & 4) != 0;
        float w = h4b ? v1 : v0, wS = h4b ? v0 : v1;
        w += __shfl_xor(wS, 4);
        // finish lane fold
        w += __shfl_xor(w, 2);
        w += __shfl_xor(w, 1);
        // lane r5 holds token T = bit4*4 + bit3*2 + bit2
        if ((r5 & 3) == 0) {
            const int T = ((r5 >> 4) & 1) * 4 + ((r5 >> 3) & 1) * 2 + ((r5 >> 2) & 1);
            clog[T][c] = w;
        }
    }
    __syncthreads();   // four quarter-waves fill each token's clog row

    // ---- per wave: finish 2 tokens (softmax + member), R23 verbatim ----
    const int r8 = lane & 7;
    const int g8 = lane >> 3;
    const float4* ie4 = reinterpret_cast<const float4*>(item_emb);

    #pragma unroll
    for (int p = 0; p < 2; ++p) {
        const int t  = wave * 2 + p;           // local slot 0..7
        const int gt = list[t0 + t];           // real token id
        const int tgt  = targets[gt];
        const int tc   = cluster_assign[tgt];
        const int tpos = in_cluster_id[tgt];
        const float msk = item_mask[gt];

        // cluster softmax + argmax (first-index tiebreak)
        const float v0 = clog[t][lane];
        const float v1 = clog[t][lane + 64];
        const float v2 = clog[t][lane + 128];
        const float v3 = clog[t][lane + 192];
        float bv = v0; int bi = lane;
        if (v1 > bv) { bv = v1; bi = lane + 64;  }
        if (v2 > bv) { bv = v2; bi = lane + 128; }
        if (v3 > bv) { bv = v3; bi = lane + 192; }
        #pragma unroll
        for (int m = 32; m > 0; m >>= 1) {
            const float ov = __shfl_xor(bv, m);
            const int   oi = __shfl_xor(bi, m);
            if (ov > bv || (ov == bv && oi < bi)) { bv = ov; bi = oi; }
        }
        float e = expf(v0 - bv) + expf(v1 - bv) + expf(v2 - bv) + expf(v3 - bv);
        #pragma unroll
        for (int m = 32; m > 0; m >>= 1) e += __shfl_xor(e, m);
        const float lse = bv + logf(e);
        const float tlpc = clog[t][tc] - lse;

        // ---- member: 8-lane groups; block-mates share tc -> L1/L2 hits ----
        float4 hme[12];
        #pragma unroll
        for (int i = 0; i < 12; ++i)
            hme[i] = h4[(size_t)gt * D4 + i * 8 + r8];
        const int* crow = cluster_idx + (size_t)tc * MCS;
        #pragma unroll 2
        for (int it = 0; it < 8; ++it) {
            const int id = crow[it * 8 + g8];   // always >= 0 for slot < 64
            const float4* ir = ie4 + (size_t)id * D4;
            float pa = 0.f;
            #pragma unroll
            for (int i = 0; i < 12; ++i) pa += dot4(ir[i * 8 + r8], hme[i]);
            pa += __shfl_xor(pa, 1);
            pa += __shfl_xor(pa, 2);
            pa += __shfl_xor(pa, 4);
            if (r8 == 0) mlog[t][it * 8 + g8] = pa;
        }
        const float w0 = mlog[t][lane];
        float mx = w0;
        #pragma unroll
        for (int m = 32; m > 0; m >>= 1) mx = fmaxf(mx, __shfl_xor(mx, m));
        float e2 = expf(w0 - mx);
        #pragma unroll
        for (int m = 32; m > 0; m >>= 1) e2 += __shfl_xor(e2, m);
        const float tlpi = mlog[t][tpos] - (mx + logf(e2));

        if (lane == 0) {
            ws[NTOK + gt]     = msk;
            ws[2 * NTOK + gt] = tlpc;
            ws[3 * NTOK + gt] = tlpi;
            ws[4 * NTOK + gt] = (bi == tc) ? 1.f : 0.f;
        }
    }
}

// ---------- D3: deterministic final reduction ----------
__global__ __launch_bounds__(1024) void hs_final(
    const float* __restrict__ ws, float* __restrict__ out)
{
    __shared__ double red[5][1024];
    const int tid = threadIdx.x;
    double a0 = 0, a1 = 0, a2 = 0, a3 = 0, a4 = 0;
    for (int i = tid; i < NTOK; i += 1024) {
        const float msk  = ws[NTOK + i];
        const float tlpc = ws[2 * NTOK + i];
        const float tlpi = ws[3 * NTOK + i];
        a0 += (double)(-(tlpc + tlpi) * msk);
        a1 += (double)msk;
        a2 += (double)tlpc;
        a3 += (double)tlpi;
        a4 += (double)ws[4 * NTOK + i];
    }
    red[0][tid] = a0; red[1][tid] = a1; red[2][tid] = a2;
    red[3][tid] = a3; red[4][tid] = a4;
    __syncthreads();
    for (int s2 = 512; s2 > 0; s2 >>= 1) {
        if (tid < s2) {
            red[0][tid] += red[0][tid + s2];
            red[1][tid] += red[1][tid + s2];
            red[2][tid] += red[2][tid + s2];
            red[3][tid] += red[3][tid + s2];
            red[4][tid] += red[4][tid + s2];
        }
        __syncthreads();
    }
    if (tid == 0) {
        out[0] = (float)(red[0][0] / (red[1][0] + 1e-8));
        out[1] = (float)(-red[2][0] / (double)NTOK);
        out[2] = (float)(-red[3][0] / (double)NTOK);
        out[3] = (float)(red[4][0] / (double)NTOK);
    }
}

extern "C" void kernel_launch(void* const* d_in, const int* in_sizes, int n_in,
                              void* d_out, int out_size, void* d_ws, size_t ws_size,
                              hipStream_t stream) {
    const float* hidden         = (const float*)d_in[0];
    const float* item_emb       = (const float*)d_in[1];
    const float* cluster_emb    = (const float*)d_in[2];
    const float* item_mask      = (const float*)d_in[3];
    const int*   targets        = (const int*)d_in[4];
    const int*   cluster_assign = (const int*)d_in[5];
    const int*   cluster_idx    = (const int*)d_in[6];
    const int*   in_cluster_id  = (const int*)d_in[7];

    float* out = (float*)d_out;
    float* ws  = (float*)d_ws;
    int*   wsI = (int*)(ws + 5 * NTOK);

    const size_t dummy_elems = (size_t)NTOK * NUM_ITEMS; // 67,108,864 zeros

    hs_fill_meta<<<NFILLB + 1, 256, 0, stream>>>(
        targets, cluster_assign, out, wsI);
    hs_compute<<<NCB, 256, 0, stream>>>(
        hidden, item_emb, cluster_emb, item_mask, targets,
        cluster_assign, cluster_idx, in_cluster_id, wsI, ws);
    hs_final<<<1, 1024, 0, stream>>>(ws, out + dummy_elems);
}

// Round 25
// 107.886 us; speedup vs baseline: 1.1200x; 1.1200x over previous
//
#include <hip/hip_runtime.h>
#include <math.h>

#define Ddim 384
#define D4 96                      // Ddim/4
#define NUM_ITEMS 16384
#define NUM_CLUSTERS 256
#define MCS 128                    // MAX_CLUSTER_SIZE
#define NEG_INF_F (-1e9f)
#define NTOK 4096
#define TPB 8                      // tokens per compute block
#define NCB (NTOK / TPB)           // 512 compute blocks
#define NFILLB 2048                // fill blocks

__device__ __forceinline__ float dot4(const float4& a, const float4& b) {
    return a.x * b.x + a.y * b.y + a.z * b.z + a.w * b.w;
}

// ---------- D1: pure fill (2048 blocks) + meta (block 2048) ----------
// Disjoint buffers -> safe in one grid; meta (~5us) hides under the fill.
__global__ __launch_bounds__(256) void hs_fill_meta(
    const int* __restrict__ targets, const int* __restrict__ cluster_assign,
    float* __restrict__ dummy_out, int* __restrict__ wsI)
{
    const int tid = threadIdx.x;

    if (blockIdx.x == NFILLB) {
        __shared__ int cnt[NUM_CLUSTERS], scan[NUM_CLUSTERS], cur[NUM_CLUSTERS];
        cnt[tid] = 0; cur[tid] = 0;
        __syncthreads();
        int tcv[NTOK / 256];
        #pragma unroll
        for (int i = 0; i < NTOK / 256; ++i) {
            const int t = i * 256 + tid;
            const int tc = cluster_assign[targets[t]];
            tcv[i] = tc;
            atomicAdd(&cnt[tc], 1);
        }
        __syncthreads();
        scan[tid] = cnt[tid];
        __syncthreads();
        for (int d = 1; d < 256; d <<= 1) {
            const int v = (tid >= d) ? scan[tid - d] : 0;
            __syncthreads();
            scan[tid] += v;
            __syncthreads();
        }
        wsI[tid] = scan[tid] - cnt[tid];
        if (tid == 255) wsI[256] = NTOK;
        __syncthreads();
        #pragma unroll
        for (int i = 0; i < NTOK / 256; ++i) {
            const int t = i * 256 + tid;
            const int tc = tcv[i];
            const int p = atomicAdd(&cur[tc], 1);
            wsI[257 + (scan[tc] - cnt[tc]) + p] = t;
        }
        return;
    }

    const size_t base = (size_t)blockIdx.x * 256 + tid;
    float4 z; z.x = z.y = z.z = z.w = 0.f;
    float4* o4 = reinterpret_cast<float4*>(dummy_out) + base;
    #pragma unroll 8
    for (int i = 0; i < 32; ++i)
        o4[(size_t)i * (NFILLB * 256)] = z;
}

// ---------- D2: compute over CLUSTER-SORTED token list (R23, best) ----------
// Tokens in a block share (mostly) one target cluster -> the block's member
// gathers hit the same 96 KB row-set in L1/L2 instead of streaming ~400 MB.
// Per-token results are independent of processing order -> deterministic.
__global__ __launch_bounds__(512, 2) void hs_compute(
    const float* __restrict__ hidden,
    const float* __restrict__ item_emb,
    const float* __restrict__ cluster_emb,
    const float* __restrict__ item_mask,
    const int*   __restrict__ targets,
    const int*   __restrict__ cluster_assign,
    const int*   __restrict__ cluster_idx,
    const int*   __restrict__ in_cluster_id,
    const int*   __restrict__ wsI,
    float* __restrict__ ws)
{
    const int cb   = blockIdx.x;           // 0..511
    const int tid  = threadIdx.x;
    const int t0   = cb * TPB;
    const int lane = tid & 63;
    const int wave = tid >> 6;             // 0..7
    const int wq   = wave & 1;             // token quad (slots wq*4..+3)
    const int wqt  = wave >> 1;            // 64-cluster quarter 0..3
    const int q    = lane >> 4;            // cluster subgroup 0..3
    const int r    = lane & 15;            // 16-lane D-split

    __shared__ float clog[TPB][NUM_CLUSTERS];   // 8 KB
    __shared__ float mlog[TPB][64];             // 2 KB

    const int* list = wsI + 257;            // cluster-sorted token ids

    // ---- cluster logits: wave covers 64 clusters x 4 (sorted) tokens ----
    const float4* h4 = reinterpret_cast<const float4*>(hidden);
    int tok[4];
    #pragma unroll
    for (int j = 0; j < 4; ++j) tok[j] = list[t0 + wq * 4 + j];
    float4 hf[4][6];
    #pragma unroll
    for (int j = 0; j < 4; ++j)
        #pragma unroll
        for (int i = 0; i < 6; ++i)
            hf[j][i] = h4[(size_t)tok[j] * D4 + i * 16 + r];

    const float4* ce4 = reinterpret_cast<const float4*>(cluster_emb);
    #pragma unroll 2
    for (int it = 0; it < 16; ++it) {
        const int c = wqt * 64 + it * 4 + q;
        float4 ce[6];
        #pragma unroll
        for (int i = 0; i < 6; ++i) ce[i] = ce4[(size_t)c * D4 + i * 16 + r];
        float a0 = 0.f, a1 = 0.f, a2 = 0.f, a3 = 0.f;
        #pragma unroll
        for (int i = 0; i < 6; ++i) {
            a0 += dot4(ce[i], hf[0][i]);
            a1 += dot4(ce[i], hf[1][i]);
            a2 += dot4(ce[i], hf[2][i]);
            a3 += dot4(ce[i], hf[3][i]);
        }
        // fold 4 accumulators over 16 lanes: 5 shuffles total
        const bool hi8 = (r & 8) != 0;
        float u  = hi8 ? a1 : a0;
        float uS = hi8 ? a0 : a1;
        u += __shfl_xor(uS, 8);
        float w  = hi8 ? a3 : a2;
        float wS = hi8 ? a2 : a3;
        w += __shfl_xor(wS, 8);
        const bool hi4 = (r & 4) != 0;
        float zv = hi4 ? w : u;
        float zS = hi4 ? u : w;
        zv += __shfl_xor(zS, 4);
        zv += __shfl_xor(zv, 2);
        zv += __shfl_xor(zv, 1);
        if ((r & 3) == 0) {
            const int m = (r >> 2) & 3;               // class -> slot {0,2,1,3}
            const int tokj = (m == 1) ? 2 : (m == 2) ? 1 : m;
            clog[wq * 4 + tokj][c] = zv;
        }
    }
    __syncthreads();   // four quarter-waves fill each slot's clog row

    // ---- per wave: finish ONE (sorted) token ----
    const int r8 = lane & 7;
    const int g8 = lane >> 3;
    const float4* ie4 = reinterpret_cast<const float4*>(item_emb);

    const int t  = wave;                   // local slot
    const int gt = list[t0 + t];           // real token id
    const int tgt  = targets[gt];
    const int tc   = cluster_assign[tgt];
    const int tpos = in_cluster_id[tgt];
    const float msk = item_mask[gt];

    // cluster softmax + argmax (first-index tiebreak)
    const float v0 = clog[t][lane];
    const float v1 = clog[t][lane + 64];
    const float v2 = clog[t][lane + 128];
    const float v3 = clog[t][lane + 192];
    float bv = v0; int bi = lane;
    if (v1 > bv) { bv = v1; bi = lane + 64;  }
    if (v2 > bv) { bv = v2; bi = lane + 128; }
    if (v3 > bv) { bv = v3; bi = lane + 192; }
    #pragma unroll
    for (int m = 32; m > 0; m >>= 1) {
        const float ov = __shfl_xor(bv, m);
        const int   oi = __shfl_xor(bi, m);
        if (ov > bv || (ov == bv && oi < bi)) { bv = ov; bi = oi; }
    }
    float e = expf(v0 - bv) + expf(v1 - bv) + expf(v2 - bv) + expf(v3 - bv);
    #pragma unroll
    for (int m = 32; m > 0; m >>= 1) e += __shfl_xor(e, m);
    const float lse = bv + logf(e);
    const float tlpc = clog[t][tc] - lse;

    // ---- member: 8-lane groups; block-mates share tc -> L1/L2 hits ----
    float4 hme[12];
    #pragma unroll
    for (int i = 0; i < 12; ++i)
        hme[i] = h4[(size_t)gt * D4 + i * 8 + r8];
    const int* crow = cluster_idx + (size_t)tc * MCS;
    #pragma unroll 2
    for (int it = 0; it < 8; ++it) {
        const int id = crow[it * 8 + g8];   // always >= 0 for slot < 64
        const float4* ir = ie4 + (size_t)id * D4;
        float pa = 0.f;
        #pragma unroll
        for (int i = 0; i < 12; ++i) pa += dot4(ir[i * 8 + r8], hme[i]);
        pa += __shfl_xor(pa, 1);
        pa += __shfl_xor(pa, 2);
        pa += __shfl_xor(pa, 4);
        if (r8 == 0) mlog[t][it * 8 + g8] = pa;
    }
    // wave-local softmax over 64 slots (exact: slots 64..127 are masked)
    const float w0 = mlog[t][lane];
    float mx = w0;
    #pragma unroll
    for (int m = 32; m > 0; m >>= 1) mx = fmaxf(mx, __shfl_xor(mx, m));
    float e2 = expf(w0 - mx);
    #pragma unroll
    for (int m = 32; m > 0; m >>= 1) e2 += __shfl_xor(e2, m);
    const float tlpi = mlog[t][tpos] - (mx + logf(e2));

    if (lane == 0) {
        ws[NTOK + gt]     = msk;
        ws[2 * NTOK + gt] = tlpc;
        ws[3 * NTOK + gt] = tlpi;
        ws[4 * NTOK + gt] = (bi == tc) ? 1.f : 0.f;
    }
}

// ---------- D3: deterministic final reduction ----------
__global__ __launch_bounds__(1024) void hs_final(
    const float* __restrict__ ws, float* __restrict__ out)
{
    __shared__ double red[5][1024];
    const int tid = threadIdx.x;
    double a0 = 0, a1 = 0, a2 = 0, a3 = 0, a4 = 0;
    for (int i = tid; i < NTOK; i += 1024) {
        const float msk  = ws[NTOK + i];
        const float tlpc = ws[2 * NTOK + i];
        const float tlpi = ws[3 * NTOK + i];
        a0 += (double)(-(tlpc + tlpi) * msk);
        a1 += (double)msk;
        a2 += (double)tlpc;
        a3 += (double)tlpi;
        a4 += (double)ws[4 * NTOK + i];
    }
    red[0][tid] = a0; red[1][tid] = a1; red[2][tid] = a2;
    red[3][tid] = a3; red[4][tid] = a4;
    __syncthreads();
    for (int s2 = 512; s2 > 0; s2 >>= 1) {
        if (tid < s2) {
            red[0][tid] += red[0][tid + s2];
            red[1][tid] += red[1][tid + s2];
            red[2][tid] += red[2][tid + s2];
            red[3][tid] += red[3][tid + s2];
            red[4][tid] += red[4][tid + s2];
        }
        __syncthreads();
    }
    if (tid == 0) {
        out[0] = (float)(red[0][0] / (red[1][0] + 1e-8));
        out[1] = (float)(-red[2][0] / (double)NTOK);
        out[2] = (float)(-red[3][0] / (double)NTOK);
        out[3] = (float)(red[4][0] / (double)NTOK);
    }
}

extern "C" void kernel_launch(void* const* d_in, const int* in_sizes, int n_in,
                              void* d_out, int out_size, void* d_ws, size_t ws_size,
                              hipStream_t stream) {
    const float* hidden         = (const float*)d_in[0];
    const float* item_emb       = (const float*)d_in[1];
    const float* cluster_emb    = (const float*)d_in[2];
    const float* item_mask      = (const float*)d_in[3];
    const int*   targets        = (const int*)d_in[4];
    const int*   cluster_assign = (const int*)d_in[5];
    const int*   cluster_idx    = (const int*)d_in[6];
    const int*   in_cluster_id  = (const int*)d_in[7];

    float* out = (float*)d_out;
    float* ws  = (float*)d_ws;
    int*   wsI = (int*)(ws + 5 * NTOK);

    const size_t dummy_elems = (size_t)NTOK * NUM_ITEMS; // 67,108,864 zeros

    hs_fill_meta<<<NFILLB + 1, 256, 0, stream>>>(
        targets, cluster_assign, out, wsI);
    hs_compute<<<NCB, 512, 0, stream>>>(
        hidden, item_emb, cluster_emb, item_mask, targets,
        cluster_assign, cluster_idx, in_cluster_id, wsI, ws);
    hs_final<<<1, 1024, 0, stream>>>(ws, out + dummy_elems);
}